// Round 15
// baseline (414.789 us; speedup 1.0000x reference)
//
#include <hip/hip_runtime.h>
#include <hip/hip_bf16.h>

// ---------------------------------------------------------------------------
// GraphConvEncoder: 2-layer GraphConv, transform-then-aggregate.
// R15 = R12 resubmitted verbatim (R12/R13/R14 all died to
// GPUAcquisitionTimeout -- no data). R12 = R11's gemm merge with the LAUNCH
// BUG FIXED: R11 launched 2*CTOT threads into __launch_bounds__(CTOT)
// kernels -> invalid launch, gemms never ran, absmax=100. Geometry is
// THREADS = 2*CTOT (2 row-wave-groups x CTOT/64 col-wave-groups x 64 lanes);
// bounds __launch_bounds__(2*CTOT, 2). Merge rationale: gemm1's old
// dim3(gblk,2) grid read x TWICE (51.2MB duplicate stream); merged block
// reads it once. Geometry re-audited r14: wave decomp, Z strides, Wb row
// ranges, VGPR budget all check out.
// CSR: bucket_scatter2@1024thr (R10) + scan_bases + sort_bucket (R9, zero
// per-edge global atomics -- R7 measured ~32B HBM write per global atomic).
// aggs: R0 16-edge hot loop + f32x2 accs (R10) + bf16 Z (R3).
// ---------------------------------------------------------------------------

#define EB 8192       // edges per scatter block (measured best; finer => amp)
#define NB_MAX 512    // max buckets (N <= 131072)
#define BCAP 12288    // per-bucket capacity (mean 8184, sigma ~90; 12/thread)

typedef __attribute__((ext_vector_type(8))) short bf16x8;
typedef __attribute__((ext_vector_type(4))) float f32x4;
typedef __attribute__((ext_vector_type(2))) float f32x2;

__device__ __forceinline__ uint pack_bf16x2(float a, float b) {
    __hip_bfloat162 p = __float22bfloat162_rn(make_float2(a, b));
    return *(uint*)&p;  // low = a, high = b
}

__device__ __forceinline__ uchar pack_fp8(float v) {
    uint p = __builtin_amdgcn_cvt_pk_fp8_f32(v, v, 0, false);
    return (uchar)(p & 0xff);
}

__device__ __forceinline__ float bflo(uint g) { return __uint_as_float(g << 16); }
__device__ __forceinline__ float bfhi(uint g) { return __uint_as_float(g & 0xffff0000u); }

__device__ __forceinline__ ushort bf16u(float v) {
    __hip_bfloat16 hb = __float2bfloat16(v);
    return *(ushort*)&hb;
}

// ---------------- L1: bucket scatter (EB=8192, 1024 threads -- R10) --------

__global__ __launch_bounds__(1024) void bucket_scatter2(const int* __restrict__ src,
                                                        const int* __restrict__ dst, int E,
                                                        int NB, int* __restrict__ bcnt,
                                                        uint* __restrict__ ebuf) {
    __shared__ int hloc[NB_MAX];
    __shared__ int cur[NB_MAX];
    int t = threadIdx.x, blk = blockIdx.x;
    for (int i = t; i < NB; i += 1024) hloc[i] = 0;
    __syncthreads();
    int e0 = blk * EB, e1 = min(E, e0 + EB);
    for (int e = e0 + t; e < e1; e += 1024) atomicAdd(&hloc[dst[e] >> 8], 1);
    __syncthreads();
    for (int i = t; i < NB; i += 1024) {
        int c = hloc[i];
        cur[i] = (c > 0) ? atomicAdd(&bcnt[i], c) : 0;
    }
    __syncthreads();
    for (int e = e0 + t; e < e1; e += 1024) {
        int d = dst[e];
        int b = d >> 8;
        int p = atomicAdd(&cur[b], 1);
        if (p < BCAP)
            ebuf[(size_t)b * BCAP + p] = ((uint)(d & 255) << 24) | (uint)src[e];
    }
}

// exclusive scan of clamped bcnt -> bbase (one block; NB <= 512)
__global__ __launch_bounds__(512) void scan_bases(const int* __restrict__ bcnt, int NB,
                                                  int* __restrict__ bbase) {
    __shared__ int s[512];
    int t = threadIdx.x;
    int v = (t < NB) ? min(bcnt[t], BCAP) : 0;
    s[t] = v;
    __syncthreads();
    for (int off = 1; off < 512; off <<= 1) {
        int u = (t >= off) ? s[t - off] : 0;
        __syncthreads();
        s[t] += u;
        __syncthreads();
    }
    if (t < NB) bbase[t] = s[t] - v;
}

// ---------------- L2: sort one bucket -> rowptr + col (no global atomics) --

__global__ __launch_bounds__(1024) void sort_bucket(const uint* __restrict__ ebuf,
                                                    const int* __restrict__ bcnt,
                                                    const int* __restrict__ bbase,
                                                    int NB, int N, int E,
                                                    int* __restrict__ rowptr,
                                                    int* __restrict__ col) {
    __shared__ int hist[16][256];
    __shared__ int s[256];
    int b = blockIdx.x, t = threadIdx.x;
    int w = t >> 6;
    int n_e = min(bcnt[b], BCAP);
    int gbase = bbase[b];
    const uint* eb = ebuf + (size_t)b * BCAP;

    for (int i = t; i < 4096; i += 1024) ((int*)hist)[i] = 0;
    __syncthreads();

    uint er[12];
#pragma unroll
    for (int k = 0; k < 12; ++k) {
        int e = t + k * 1024;
        if (e < n_e) {
            uint ev = eb[e];
            er[k] = ev;
            atomicAdd(&hist[w][ev >> 24], 1);
        }
    }
    __syncthreads();

    int tot = 0;
    if (t < 256) {
        int rs = 0;
#pragma unroll
        for (int ww = 0; ww < 16; ++ww) {
            int c = hist[ww][t];
            hist[ww][t] = rs;   // prefix within node t
            rs += c;
        }
        tot = rs;
        s[t] = rs;
    }
    __syncthreads();
    for (int off = 1; off < 256; off <<= 1) {
        int u = (t < 256 && t >= off) ? s[t - off] : 0;
        __syncthreads();
        if (t < 256) s[t] += u;
        __syncthreads();
    }
    if (t < 256) {
        int start = gbase + s[t] - tot;  // global exclusive start of node t
        int node = (b << 8) + t;
        if (node < N) rowptr[node] = start;
#pragma unroll
        for (int ww = 0; ww < 16; ++ww) hist[ww][t] += start;  // abs cursors
    }
    if (b == NB - 1 && t == 0) rowptr[N] = E;
    __syncthreads();

#pragma unroll
    for (int k = 0; k < 12; ++k) {
        int e = t + k * 1024;
        if (e < n_e) {
            uint ev = er[k];
            int p = atomicAdd(&hist[w][ev >> 24], 1);
            col[p] = (int)(ev & 0xFFFFFFu);
        }
    }
}

// ---------------- weight pre-convert (f32 -> bf16, once per launch) --------

__global__ __launch_bounds__(256) void prep_w(const float* __restrict__ W1_rel,
                                              const float* __restrict__ W1_root,
                                              const float* __restrict__ W2_rel,
                                              const float* __restrict__ W2_root,
                                              ushort* __restrict__ Wb1,
                                              ushort* __restrict__ Wb2) {
    int t = blockIdx.x * 256 + threadIdx.x;
    if (t < 8192) {  // 256*128 / 4
        int idx = t * 4;
        int row = idx >> 7, c = idx & 127;
        const float* src = (row < 128) ? W1_rel + (size_t)row * 128 + c
                                       : W1_root + (size_t)(row - 128) * 128 + c;
        float4 v = *(const float4*)src;
        uint2 u;
        u.x = pack_bf16x2(v.x, v.y);
        u.y = pack_bf16x2(v.z, v.w);
        *(uint2*)(Wb1 + idx) = u;
    } else if (t < 12288) {  // + 128*128 / 4
        int idx = (t - 8192) * 4;
        int row = idx >> 7, c = idx & 127;
        const float* src = (row < 64) ? W2_rel + (size_t)row * 128 + c
                                      : W2_root + (size_t)(row - 64) * 128 + c;
        float4 v = *(const float4*)src;
        uint2 u;
        u.x = pack_bf16x2(v.x, v.y);
        u.y = pack_bf16x2(v.z, v.w);
        *(uint2*)(Wb2 + idx) = u;
    }
}

// ---------------- MFMA dual GEMM, direct-register (no LDS, no barriers) ----
// One block = 2*CTOT threads: 128 rows x CTOT cols (CY cols of Y fp8|bf16,
// CTOT-CY cols of Z bf16(bias + X@Wb^T)). Waves: wm in {0,1} x wn in
// {0..CTOT/64-1}. x read ONCE per tile.

template <int CY, int CTOT, bool A_BF16, bool Y_FP8>
__global__ __launch_bounds__(2 * CTOT, 2) void gemm_direct(const void* __restrict__ Aptr,
                                                           const ushort* __restrict__ Wb16,
                                                           const float* __restrict__ bias,
                                                           void* __restrict__ Yout,
                                                           ushort* __restrict__ Z,
                                                           int n_rows) {
    constexpr int WN = CTOT / 64;  // waves along columns
    const int t = threadIdx.x;
    const int lane = t & 63;
    const int wave = t >> 6;       // 0 .. 2*WN-1
    const int wm = wave / WN, wn = wave % WN;
    const int row0 = blockIdx.x * 128;
    const int fr = lane & 15;
    const int quad = lane >> 4;

    f32x4 acc[4][4];
#pragma unroll
    for (int i = 0; i < 4; i++)
#pragma unroll
        for (int j = 0; j < 4; j++) acc[i][j] = (f32x4){0.f, 0.f, 0.f, 0.f};

    int ar[4];
#pragma unroll
    for (int mt = 0; mt < 4; ++mt) {
        int r = row0 + wm * 64 + mt * 16 + fr;
        ar[mt] = (r < n_rows) ? r : (n_rows - 1);  // clamp; stores are guarded
    }
    const int brbase = wn * 64;

#pragma unroll
    for (int kk = 0; kk < 4; ++kk) {
        const int kb = kk * 32 + quad * 8;
        bf16x8 a[4], b[4];
#pragma unroll
        for (int mt = 0; mt < 4; ++mt) {
            if (A_BF16) {
                a[mt] = *(const bf16x8*)((const ushort*)Aptr + (size_t)ar[mt] * 128 + kb);
            } else {
                const float* p = (const float*)Aptr + (size_t)ar[mt] * 128 + kb;
                float4 v0 = *(const float4*)p;
                float4 v1 = *(const float4*)(p + 4);
                uint4 u;
                u.x = pack_bf16x2(v0.x, v0.y);
                u.y = pack_bf16x2(v0.z, v0.w);
                u.z = pack_bf16x2(v1.x, v1.y);
                u.w = pack_bf16x2(v1.z, v1.w);
                a[mt] = *(bf16x8*)&u;
            }
        }
#pragma unroll
        for (int nt = 0; nt < 4; ++nt)
            b[nt] = *(const bf16x8*)(Wb16 + (size_t)(brbase + nt * 16 + fr) * 128 + kb);
#pragma unroll
        for (int mt = 0; mt < 4; ++mt)
#pragma unroll
            for (int nt = 0; nt < 4; ++nt)
                acc[mt][nt] = __builtin_amdgcn_mfma_f32_16x16x32_bf16(
                    a[mt], b[nt], acc[mt][nt], 0, 0, 0);
    }

    // C/D layout: col = lane&15, row = quad*4 + reg
#pragma unroll
    for (int nt = 0; nt < 4; ++nt) {
        int gcol = wn * 64 + nt * 16 + fr;
        if (gcol < CY) {
#pragma unroll
            for (int mt = 0; mt < 4; ++mt) {
#pragma unroll
                for (int r = 0; r < 4; ++r) {
                    int grow = row0 + wm * 64 + mt * 16 + quad * 4 + r;
                    if (grow < n_rows) {
                        if (Y_FP8) {
                            ((uchar*)Yout)[(size_t)grow * CY + gcol] =
                                pack_fp8(acc[mt][nt][r]);
                        } else {
                            ((ushort*)Yout)[(size_t)grow * CY + gcol] =
                                bf16u(acc[mt][nt][r]);
                        }
                    }
                }
            }
        } else {
            float bv = bias[gcol - CY];
#pragma unroll
            for (int mt = 0; mt < 4; ++mt) {
#pragma unroll
                for (int r = 0; r < 4; ++r) {
                    int grow = row0 + wm * 64 + mt * 16 + quad * 4 + r;
                    if (grow < n_rows)
                        Z[(size_t)grow * CY + (gcol - CY)] = bf16u(acc[mt][nt][r] + bv);
                }
            }
        }
    }
}

// ---------------- aggregation (CSR wave-per-node, 16-edge loop, pk accs) ---

#define ACC_FP8(v)                                                           \
    {                                                                        \
        f32x2 p;                                                             \
        p = __builtin_amdgcn_cvt_pk_f32_fp8((v).x, false); acc2[0] += p;     \
        p = __builtin_amdgcn_cvt_pk_f32_fp8((v).x, true);  acc2[1] += p;     \
        p = __builtin_amdgcn_cvt_pk_f32_fp8((v).y, false); acc2[2] += p;     \
        p = __builtin_amdgcn_cvt_pk_f32_fp8((v).y, true);  acc2[3] += p;     \
        p = __builtin_amdgcn_cvt_pk_f32_fp8((v).z, false); acc2[4] += p;     \
        p = __builtin_amdgcn_cvt_pk_f32_fp8((v).z, true);  acc2[5] += p;     \
        p = __builtin_amdgcn_cvt_pk_f32_fp8((v).w, false); acc2[6] += p;     \
        p = __builtin_amdgcn_cvt_pk_f32_fp8((v).w, true);  acc2[7] += p;     \
    }

__global__ __launch_bounds__(256) void agg_relu_l1(const uchar* __restrict__ Y1,
                                                   const ushort* __restrict__ Z1,
                                                   const int* __restrict__ rowptr,
                                                   const int* __restrict__ col,
                                                   ushort* __restrict__ h, int n_nodes) {
    int node = (blockIdx.x * 256 + threadIdx.x) >> 6;
    if (node >= n_nodes) return;
    int lane = threadIdx.x & 63;
    int sub = lane >> 3;   // edge slot within group of 8
    int cg  = lane & 7;    // channel group: channels cg*16 .. +15
    int beg = rowptr[node], end = rowptr[node + 1];
    f32x2 acc2[8];
#pragma unroll
    for (int i = 0; i < 8; i++) acc2[i] = (f32x2){0.f, 0.f};

    int e = beg;
    for (; e + 16 <= end; e += 16) {  // 2 groups in flight (R0 structure)
        int s0 = col[e + sub];
        int s1 = col[e + 8 + sub];
        uint4 v0 = *(const uint4*)(Y1 + (size_t)s0 * 128 + cg * 16);
        uint4 v1 = *(const uint4*)(Y1 + (size_t)s1 * 128 + cg * 16);
        ACC_FP8(v0);
        ACC_FP8(v1);
    }
    for (; e < end; e += 8) {  // masked tail groups
        int ee = e + sub;
        uint4 v = make_uint4(0u, 0u, 0u, 0u);
        if (ee < end)
            v = *(const uint4*)(Y1 + (size_t)col[ee] * 128 + cg * 16);
        ACC_FP8(v);
    }

#pragma unroll
    for (int off = 8; off < 64; off <<= 1)
#pragma unroll
        for (int i = 0; i < 8; i++) {
            f32x2 o;
            o[0] = __shfl_xor(acc2[i][0], off, 64);
            o[1] = __shfl_xor(acc2[i][1], off, 64);
            acc2[i] += o;
        }

    if (sub == 0) {  // lanes 0..7: channels cg*16..+15 (Z1 bf16)
        const uint4* zp = (const uint4*)(Z1 + (size_t)node * 128 + cg * 16);
        uint4 za = zp[0], zb = zp[1];
        float z[16] = {bflo(za.x), bfhi(za.x), bflo(za.y), bfhi(za.y),
                       bflo(za.z), bfhi(za.z), bflo(za.w), bfhi(za.w),
                       bflo(zb.x), bfhi(zb.x), bflo(zb.y), bfhi(zb.y),
                       bflo(zb.z), bfhi(zb.z), bflo(zb.w), bfhi(zb.w)};
        uint o[8];
#pragma unroll
        for (int q = 0; q < 8; ++q) {
            float r0 = acc2[q][0] + z[q * 2 + 0];
            float r1 = acc2[q][1] + z[q * 2 + 1];
            r0 = r0 > 0.f ? r0 : 0.f;
            r1 = r1 > 0.f ? r1 : 0.f;
            o[q] = pack_bf16x2(r0, r1);
        }
        uint* hp = (uint*)(h + (size_t)node * 128) + cg * 8;
        *(uint4*)(hp + 0) = make_uint4(o[0], o[1], o[2], o[3]);
        *(uint4*)(hp + 4) = make_uint4(o[4], o[5], o[6], o[7]);
    }
}

#define ACC_BF16(v)                                       \
    {                                                     \
        acc2[0] += (f32x2){bflo((v).x), bfhi((v).x)};     \
        acc2[1] += (f32x2){bflo((v).y), bfhi((v).y)};     \
        acc2[2] += (f32x2){bflo((v).z), bfhi((v).z)};     \
        acc2[3] += (f32x2){bflo((v).w), bfhi((v).w)};     \
    }

__global__ __launch_bounds__(256) void agg_l2(const ushort* __restrict__ Y2,
                                              const ushort* __restrict__ Z2,
                                              const int* __restrict__ rowptr,
                                              const int* __restrict__ col,
                                              float* __restrict__ out, int n_nodes) {
    int node = (blockIdx.x * 256 + threadIdx.x) >> 6;
    if (node >= n_nodes) return;
    int lane = threadIdx.x & 63;
    int sub = lane >> 3;
    int cg  = lane & 7;   // channels cg*8 .. +7
    int beg = rowptr[node], end = rowptr[node + 1];
    f32x2 acc2[4];
#pragma unroll
    for (int i = 0; i < 4; i++) acc2[i] = (f32x2){0.f, 0.f};

    int e = beg;
    for (; e + 16 <= end; e += 16) {
        int s0 = col[e + sub];
        int s1 = col[e + 8 + sub];
        uint4 v0 = *(const uint4*)(Y2 + (size_t)s0 * 64 + cg * 8);
        uint4 v1 = *(const uint4*)(Y2 + (size_t)s1 * 64 + cg * 8);
        ACC_BF16(v0);
        ACC_BF16(v1);
    }
    for (; e < end; e += 8) {
        int ee = e + sub;
        uint4 v = make_uint4(0u, 0u, 0u, 0u);
        if (ee < end)
            v = *(const uint4*)(Y2 + (size_t)col[ee] * 64 + cg * 8);
        ACC_BF16(v);
    }

#pragma unroll
    for (int off = 8; off < 64; off <<= 1)
#pragma unroll
        for (int i = 0; i < 4; i++) {
            f32x2 o;
            o[0] = __shfl_xor(acc2[i][0], off, 64);
            o[1] = __shfl_xor(acc2[i][1], off, 64);
            acc2[i] += o;
        }

    if (sub == 0) {  // lanes 0..7: channels cg*8..+7 (Z2 bf16, 16 B)
        uint4 z = *(const uint4*)(Z2 + (size_t)node * 64 + cg * 8);
        float4 o0 = {acc2[0][0] + bflo(z.x), acc2[0][1] + bfhi(z.x),
                     acc2[1][0] + bflo(z.y), acc2[1][1] + bfhi(z.y)};
        float4 o1 = {acc2[2][0] + bflo(z.z), acc2[2][1] + bfhi(z.z),
                     acc2[3][0] + bflo(z.w), acc2[3][1] + bfhi(z.w)};
        float4* op = (float4*)(out + (size_t)node * 64 + cg * 8);
        op[0] = o0;
        op[1] = o1;
    }
}

// ---------------- launch ----------------

extern "C" void kernel_launch(void* const* d_in, const int* in_sizes, int n_in,
                              void* d_out, int out_size, void* d_ws, size_t ws_size,
                              hipStream_t stream) {
    const float* x       = (const float*)d_in[0];
    const int*   ei      = (const int*)d_in[1];
    const float* W1_rel  = (const float*)d_in[2];
    const float* b1      = (const float*)d_in[3];
    const float* W1_root = (const float*)d_in[4];
    const float* W2_rel  = (const float*)d_in[5];
    const float* b2      = (const float*)d_in[6];
    const float* W2_root = (const float*)d_in[7];
    float* out = (float*)d_out;

    const int N = in_sizes[0] / 128;
    const int E = in_sizes[1] / 2;
    const int* srcA = ei;
    const int* dstA = ei + E;
    const int NB   = (N + 255) >> 8;
    const int NBLK = (E + EB - 1) / EB;

    char* ws = (char*)d_ws;
    size_t cur = 0;
    auto alloc = [&](size_t bytes) -> void* {
        size_t o = cur;
        cur = (cur + bytes + 511) & ~(size_t)511;
        return (void*)(ws + o);
    };
    uchar*  Y1  = (uchar*)alloc((size_t)N * 128);        // fp8
    ushort* Z1  = (ushort*)alloc((size_t)N * 128 * 2);   // bf16
    ushort* h   = (ushort*)alloc((size_t)N * 128 * 2);   // bf16
    ushort* Y2  = (ushort*)alloc((size_t)N * 64 * 2);    // bf16
    ushort* Z2  = (ushort*)alloc((size_t)N * 64 * 2);    // bf16
    int* rowptr = (int*)alloc((size_t)(N + 1) * 4);
    int* colA   = (int*)alloc((size_t)E * 4);
    int* bcnt   = (int*)alloc((size_t)NB_MAX * 4);
    int* bbase  = (int*)alloc((size_t)NB_MAX * 4);
    ushort* Wb1 = (ushort*)alloc((size_t)256 * 128 * 2); // bf16 [W1_rel;W1_root]
    ushort* Wb2 = (ushort*)alloc((size_t)128 * 128 * 2); // bf16 [W2_rel;W2_root]
    uint* ebuf  = (uint*)alloc((size_t)NB * BCAP * 4);   // bucketed edges

    hipMemsetAsync(bcnt, 0, (size_t)NB * 4, stream);
    prep_w<<<48, 256, 0, stream>>>(W1_rel, W1_root, W2_rel, W2_root, Wb1, Wb2);

    bucket_scatter2<<<NBLK, 1024, 0, stream>>>(srcA, dstA, E, NB, bcnt, ebuf);
    scan_bases<<<1, 512, 0, stream>>>(bcnt, NB, bbase);
    sort_bucket<<<NB, 1024, 0, stream>>>(ebuf, bcnt, bbase, NB, N, E, rowptr, colA);

    const int gblk = (N + 127) / 128;
    gemm_direct<128, 256, false, true><<<gblk, 512, 0, stream>>>(
        x, Wb1, b1, Y1, Z1, N);
    agg_relu_l1<<<(N + 3) / 4, 256, 0, stream>>>(Y1, Z1, rowptr, colA, h, N);
    gemm_direct<64, 128, true, false><<<gblk, 256, 0, stream>>>(
        h, Wb2, b2, Y2, Z2, N);
    agg_l2<<<(N + 3) / 4, 256, 0, stream>>>(Y2, Z2, rowptr, colA, out, N);
}